// Round 5
// baseline (456.516 us; speedup 1.0000x reference)
//
#include <hip/hip_runtime.h>

typedef __attribute__((ext_vector_type(8))) short bf16x8;
typedef __attribute__((ext_vector_type(4))) float f32x4;
typedef unsigned short u16;
typedef unsigned int u32;

#define T_SEQ 2048
#define C_DIM 1024
#define NH 16
#define HD 64
#define BATCH 2

__device__ __forceinline__ u16 f2bf(float f) {
    union { float f; u32 u; } v; v.f = f;
    u32 u = v.u;
    u32 r = (u + 0x7FFFu + ((u >> 16) & 1u)) >> 16;
    return (u16)r;
}

__device__ __forceinline__ float fexp2(float x) { return __builtin_amdgcn_exp2f(x); }

// async global->LDS, 16B per lane; LDS dest is wave-uniform base + lane*16
__device__ __forceinline__ void gld_lds16(const void* g, void* l) {
    __builtin_amdgcn_global_load_lds(
        (const __attribute__((address_space(1))) void*)g,
        (__attribute__((address_space(3))) void*)l, 16, 0, 0);
}

// ---------------------------------------------------------------------------
// Transpose 4 weight matrices [C,C] f32 -> [C,C] bf16 (WT[n][k] = W[k][n])
// ---------------------------------------------------------------------------
__global__ __launch_bounds__(256) void transpose_to_bf16(
    const float* __restrict__ W0, const float* __restrict__ W1,
    const float* __restrict__ W2, const float* __restrict__ W3,
    u16* __restrict__ O0, u16* __restrict__ O1,
    u16* __restrict__ O2, u16* __restrict__ O3)
{
    __shared__ float tile[32][33];
    const float* W = blockIdx.z == 0 ? W0 : blockIdx.z == 1 ? W1 : blockIdx.z == 2 ? W2 : W3;
    u16* O = blockIdx.z == 0 ? O0 : blockIdx.z == 1 ? O1 : blockIdx.z == 2 ? O2 : O3;
    const int tx = threadIdx.x, ty = threadIdx.y;
    const int bx = blockIdx.x * 32, by = blockIdx.y * 32;
#pragma unroll
    for (int i = 0; i < 4; ++i)
        tile[ty + i * 8][tx] = W[(size_t)(by + ty + i * 8) * C_DIM + bx + tx];
    __syncthreads();
#pragma unroll
    for (int i = 0; i < 4; ++i)
        O[(size_t)(bx + ty + i * 8) * C_DIM + by + tx] = f2bf(tile[tx][ty + i * 8]);
}

// ---------------------------------------------------------------------------
// GEMM: Y[M,N] = X[M,K] @ W[K,N] + bias, WT[N,K] pre-transposed bf16.
// B staged via global_load_lds(16B); A likewise when X is bf16 (XF32=false),
// else reg-staged with fused f32->bf16.
// OMODE: 0 = bf16 row-major, 1 = f32 row-major, 2 = bf16 per-head V^T
// ---------------------------------------------------------------------------
template<bool XF32, int OMODE>
__global__ __launch_bounds__(256) void gemm_bt(
    const void* __restrict__ Xv, const u16* __restrict__ WT,
    const float* __restrict__ bias, void* __restrict__ Yv,
    int M, int N, int K)
{
    __shared__ u16 As[128 * 32];
    __shared__ u16 Bs[128 * 32];
    const int tid = threadIdx.x;
    const int w = tid >> 6, l = tid & 63;
    const int lr = l & 15, lg = l >> 4;
    const int m0 = blockIdx.y * 128, n0 = blockIdx.x * 128;
    const int wr = (w >> 1) * 64, wc = (w & 1) * 64;
    const int grow = w * 32 + (l >> 2);   // + i*16
    const int gcol = (l & 3) * 8;
    f32x4 acc[4][4] = {};

    for (int k0 = 0; k0 < K; k0 += 32) {
        __syncthreads();
        if (XF32) {
#pragma unroll
            for (int r = 0; r < 2; ++r) {
                const int idx = r * 256 + tid;      // 0..511
                const int row = idx >> 2, cg = idx & 3;
                const float* g = (const float*)Xv + (size_t)(m0 + row) * K + k0 + cg * 8;
                float4 a0 = *(const float4*)g;
                float4 a1 = *(const float4*)(g + 4);
                union { u16 h[8]; uint4 q; } pk;
                pk.h[0] = f2bf(a0.x); pk.h[1] = f2bf(a0.y);
                pk.h[2] = f2bf(a0.z); pk.h[3] = f2bf(a0.w);
                pk.h[4] = f2bf(a1.x); pk.h[5] = f2bf(a1.y);
                pk.h[6] = f2bf(a1.z); pk.h[7] = f2bf(a1.w);
                *(uint4*)&As[row * 32 + cg * 8] = pk.q;
            }
        } else {
#pragma unroll
            for (int i = 0; i < 2; ++i)
                gld_lds16((const u16*)Xv + (size_t)(m0 + grow + i * 16) * K + k0 + gcol,
                          &As[(w * 2 + i) * 512]);
        }
#pragma unroll
        for (int i = 0; i < 2; ++i)
            gld_lds16(WT + (size_t)(n0 + grow + i * 16) * K + k0 + gcol,
                      &Bs[(w * 2 + i) * 512]);
        __syncthreads();
        bf16x8 af[4], bfr[4];
#pragma unroll
        for (int i = 0; i < 4; ++i)
            af[i] = *(const bf16x8*)&As[(wr + i * 16 + lr) * 32 + lg * 8];
#pragma unroll
        for (int j = 0; j < 4; ++j)
            bfr[j] = *(const bf16x8*)&Bs[(wc + j * 16 + lr) * 32 + lg * 8];
#pragma unroll
        for (int i = 0; i < 4; ++i)
#pragma unroll
            for (int j = 0; j < 4; ++j)
                acc[i][j] = __builtin_amdgcn_mfma_f32_16x16x32_bf16(af[i], bfr[j], acc[i][j], 0, 0, 0);
    }

#pragma unroll
    for (int i = 0; i < 4; ++i) {
        const int rowb = m0 + wr + i * 16 + lg * 4;
#pragma unroll
        for (int j = 0; j < 4; ++j) {
            const int col = n0 + wc + j * 16 + lr;
            const float bv = bias[col];
            if (OMODE == 2) {
                union { u16 h[4]; uint2 q; } pk;
#pragma unroll
                for (int r = 0; r < 4; ++r) pk.h[r] = f2bf(acc[i][j][r] + bv);
                const int bb = rowb >> 11, tt = rowb & 2047;
                const int hh = col >> 6, dd = col & 63;
                u16* dst = (u16*)Yv + ((size_t)((bb * NH + hh) * HD + dd)) * T_SEQ + tt;
                *(uint2*)dst = pk.q;
            } else {
#pragma unroll
                for (int r = 0; r < 4; ++r) {
                    const float v = acc[i][j][r] + bv;
                    if (OMODE == 1)
                        ((float*)Yv)[(size_t)(rowb + r) * N + col] = v;
                    else
                        ((u16*)Yv)[(size_t)(rowb + r) * N + col] = f2bf(v);
                }
            }
        }
    }
}

// ---------------------------------------------------------------------------
// Causal attention. Block = (b, h, 16 q-rows), 8 waves split kv in 64-wide
// tiles round-robin. No LDS in the hot loop: P is transposed into the PV
// A-fragment with 8 shfl + 4 cndmask (fence-free -> cross-tile pipelining).
// ---------------------------------------------------------------------------
#define PV_QS 67                 // float stride per q-row in pvbuf
#define PV_WS (16 * PV_QS + 8)   // float stride per wave block

__global__ __launch_bounds__(512) void attn_kernel(
    const u16* __restrict__ qp, const u16* __restrict__ kp,
    const u16* __restrict__ vt, u16* __restrict__ ctx,
    float* __restrict__ attn)
{
    __shared__ float statm[8][16], statl[8][16];
    __shared__ float pvbuf[8 * PV_WS];

    const int tid = threadIdx.x;
    const int w = tid >> 6, l = tid & 63;
    const int lr = l & 15, lg = l >> 4;
    const int b = blockIdx.z, h = blockIdx.y;
    const int strip = (gridDim.x - 1) - blockIdx.x;   // heavy-first
    const int q0 = strip * 16;

    const size_t bh_off = (size_t)b * T_SEQ * C_DIM + h * HD;
    const u16* qb = qp + bh_off;
    const u16* kb = kp + bh_off;
    const u16* vtb = vt + ((size_t)(b * NH + h) * HD) * T_SEQ;
    float* ab = attn + (size_t)(b * NH + h) * T_SEQ * T_SEQ;

    const float SC = 0.125f * 1.44269504088896f;   // 1/sqrt(64) * log2(e)
    const float MNEG = -1e30f;

    const bf16x8 aq0 = *(const bf16x8*)(qb + (size_t)(q0 + lr) * C_DIM + lg * 8);
    const bf16x8 aq1 = *(const bf16x8*)(qb + (size_t)(q0 + lr) * C_DIM + 32 + lg * 8);

    const int qrow = q0 + lr;
    const int kv_end = q0 + 16;
    const int n64 = (kv_end + 63) >> 6;   // 64-wide kv tiles

    // ---- phase A: per-wave partial (m, l), in-lane per tile ----
    float ml = MNEG, ll = 0.f;
    for (int ti = w; ti < n64; ti += 8) {
        const int kvb = ti * 64;
        bf16x8 kf[4][2];
#pragma unroll
        for (int t = 0; t < 4; ++t) {
            const u16* kr = kb + (size_t)(kvb + t * 16 + lr) * C_DIM;
            kf[t][0] = *(const bf16x8*)(kr + lg * 8);
            kf[t][1] = *(const bf16x8*)(kr + 32 + lg * 8);
        }
        f32x4 s[4] = {};
#pragma unroll
        for (int t = 0; t < 4; ++t) {
            s[t] = __builtin_amdgcn_mfma_f32_16x16x32_bf16(kf[t][0], aq0, s[t], 0, 0, 0);
            s[t] = __builtin_amdgcn_mfma_f32_16x16x32_bf16(kf[t][1], aq1, s[t], 0, 0, 0);
        }
        float sv[16];
        float mt = MNEG;
#pragma unroll
        for (int t = 0; t < 4; ++t)
#pragma unroll
            for (int r = 0; r < 4; ++r) {
                float v = s[t][r] * SC;
                if (kvb + 16 * t + 4 * lg + r > qrow) v = MNEG;
                sv[t * 4 + r] = v;
                mt = fmaxf(mt, v);
            }
        const float mn = fmaxf(ml, mt);
        float e = 0.f;
#pragma unroll
        for (int i = 0; i < 16; ++i) e += fexp2(sv[i] - mn);
        ll = ll * fexp2(ml - mn) + e;
        ml = mn;
    }
#pragma unroll
    for (int d = 16; d <= 32; d <<= 1) {
        const float mo = __shfl_xor(ml, d);
        const float lo = __shfl_xor(ll, d);
        const float mn = fmaxf(ml, mo);
        ll = ll * fexp2(ml - mn) + lo * fexp2(mo - mn);
        ml = mn;
    }
    if (l < 16) { statm[w][lr] = ml; statl[w][lr] = ll; }
    __syncthreads();

    float mf = MNEG;
#pragma unroll
    for (int ww = 0; ww < 8; ++ww) mf = fmaxf(mf, statm[ww][lr]);
    float lf = 0.f;
#pragma unroll
    for (int ww = 0; ww < 8; ++ww) lf += statl[ww][lr] * fexp2(statm[ww][lr] - mf);
    const float rl = 1.f / lf;

    // ---- phase B: write normalized P + partial PV (fence-free) ----
    f32x4 cacc[4] = {};
    for (int ti = w; ti < n64; ti += 8) {
        const int kvb = ti * 64;
        bf16x8 vf[2][4];
#pragma unroll
        for (int st = 0; st < 2; ++st)
#pragma unroll
            for (int dt = 0; dt < 4; ++dt)
                vf[st][dt] = *(const bf16x8*)(vtb + (size_t)(dt * 16 + lr) * T_SEQ
                                              + kvb + st * 32 + lg * 8);
        bf16x8 kf[4][2];
#pragma unroll
        for (int t = 0; t < 4; ++t) {
            const u16* kr = kb + (size_t)(kvb + t * 16 + lr) * C_DIM;
            kf[t][0] = *(const bf16x8*)(kr + lg * 8);
            kf[t][1] = *(const bf16x8*)(kr + 32 + lg * 8);
        }
        f32x4 s[4] = {};
#pragma unroll
        for (int t = 0; t < 4; ++t) {
            s[t] = __builtin_amdgcn_mfma_f32_16x16x32_bf16(kf[t][0], aq0, s[t], 0, 0, 0);
            s[t] = __builtin_amdgcn_mfma_f32_16x16x32_bf16(kf[t][1], aq1, s[t], 0, 0, 0);
        }
#pragma unroll
        for (int st = 0; st < 2; ++st) {
            u32 pw[2][2];     // [t-within-subtile][word]
#pragma unroll
            for (int t2 = 0; t2 < 2; ++t2) {
                const int t = st * 2 + t2;
                float p[4];
#pragma unroll
                for (int r = 0; r < 4; ++r) {
                    float v = s[t][r] * SC;
                    if (kvb + 16 * t + 4 * lg + r > qrow) v = MNEG;
                    p[r] = fexp2(v - mf) * rl;
                }
                *(float4*)(ab + (size_t)qrow * T_SEQ + kvb + 16 * t + 4 * lg) =
                    make_float4(p[0], p[1], p[2], p[3]);
                pw[t2][0] = (u32)f2bf(p[0]) | ((u32)f2bf(p[1]) << 16);
                pw[t2][1] = (u32)f2bf(p[2]) | ((u32)f2bf(p[3]) << 16);
            }
            // shuffle-transpose: C-layout (kv in lg-groups of 4) -> A-frag (kv=8*lg+j)
            const int bl = lr + ((lg & 1) << 5);
            const u32 a0 = (u32)__shfl((int)pw[0][0], bl);
            const u32 a1 = (u32)__shfl((int)pw[0][1], bl);
            const u32 a2 = (u32)__shfl((int)pw[0][0], bl + 16);
            const u32 a3 = (u32)__shfl((int)pw[0][1], bl + 16);
            const u32 b0 = (u32)__shfl((int)pw[1][0], bl);
            const u32 b1 = (u32)__shfl((int)pw[1][1], bl);
            const u32 b2 = (u32)__shfl((int)pw[1][0], bl + 16);
            const u32 b3 = (u32)__shfl((int)pw[1][1], bl + 16);
            const bool hi2 = lg >= 2;
            union { u32 ww[4]; bf16x8 v; } pa;
            pa.ww[0] = hi2 ? b0 : a0;
            pa.ww[1] = hi2 ? b1 : a1;
            pa.ww[2] = hi2 ? b2 : a2;
            pa.ww[3] = hi2 ? b3 : a3;
#pragma unroll
            for (int dt = 0; dt < 4; ++dt)
                cacc[dt] = __builtin_amdgcn_mfma_f32_16x16x32_bf16(pa.v, vf[st][dt], cacc[dt], 0, 0, 0);
        }
    }

    // dump PV partials (cacc[dt][r] = ctx[q=4*lg+r][d=dt*16+lr])
    {
        float* pwv = pvbuf + w * PV_WS;
#pragma unroll
        for (int dt = 0; dt < 4; ++dt)
#pragma unroll
            for (int r = 0; r < 4; ++r)
                pwv[(4 * lg + r) * PV_QS + dt * 16 + lr] = cacc[dt][r];
    }
    __syncthreads();

    // reduce PV across waves + write ctx (bf16)
    {
        const int qq = tid >> 5;
        const int d0 = (tid & 31) * 2;
        float s0 = 0.f, s1 = 0.f;
#pragma unroll
        for (int ww = 0; ww < 8; ++ww) {
            const float* pwv = pvbuf + ww * PV_WS + qq * PV_QS;
            s0 += pwv[d0];
            s1 += pwv[d0 + 1];
        }
        union { u16 hh[2]; u32 u; } pk;
        pk.hh[0] = f2bf(s0); pk.hh[1] = f2bf(s1);
        u16* cb = ctx + bh_off;
        *(u32*)(cb + (size_t)(q0 + qq) * C_DIM + d0) = pk.u;
    }

    // zero-fill [n64*64, T) for all 16 rows
    {
        const int zs = n64 * 64;
        const int row = tid >> 5;
        const int c0 = (tid & 31) * 4;
        float* zr = ab + (size_t)(q0 + row) * T_SEQ;
        const float4 z4 = make_float4(0.f, 0.f, 0.f, 0.f);
        for (int c = zs + c0; c < T_SEQ; c += 128)
            *(float4*)(zr + c) = z4;
    }
}

// ---------------------------------------------------------------------------
extern "C" void kernel_launch(void* const* d_in, const int* in_sizes, int n_in,
                              void* d_out, int out_size, void* d_ws, size_t ws_size,
                              hipStream_t stream)
{
    const float* q  = (const float*)d_in[0];
    const float* k  = (const float*)d_in[1];
    const float* Wq = (const float*)d_in[2];
    const float* bq = (const float*)d_in[3];
    const float* Wk = (const float*)d_in[4];
    const float* bk = (const float*)d_in[5];
    const float* Wv = (const float*)d_in[6];
    const float* bv = (const float*)d_in[7];
    const float* Wo = (const float*)d_in[8];
    const float* bo = (const float*)d_in[9];
    (void)in_sizes; (void)n_in; (void)out_size; (void)ws_size;

    float* out = (float*)d_out;
    float* attn = out + (size_t)BATCH * T_SEQ * C_DIM;

    const size_t MC = (size_t)BATCH * T_SEQ * C_DIM;   // 4,194,304 elems
    u16* qp  = (u16*)d_ws;
    u16* kp  = qp + MC;
    u16* vt  = kp + MC;          // V^T: [B][H][D][T]
    u16* ctx = vt + MC;
    u16* WqT = ctx + MC;
    u16* WkT = WqT + (size_t)C_DIM * C_DIM;
    u16* WvT = WkT + (size_t)C_DIM * C_DIM;
    u16* WoT = WvT + (size_t)C_DIM * C_DIM;

    transpose_to_bf16<<<dim3(32, 32, 4), dim3(32, 8), 0, stream>>>(
        Wq, Wk, Wv, Wo, WqT, WkT, WvT, WoT);

    const int M = BATCH * T_SEQ;
    dim3 gg(C_DIM / 128, M / 128);
    gemm_bt<true,  0><<<gg, 256, 0, stream>>>(q,  WqT, bq, qp, M, C_DIM, C_DIM);
    gemm_bt<true,  0><<<gg, 256, 0, stream>>>(k,  WkT, bk, kp, M, C_DIM, C_DIM);
    gemm_bt<false, 2><<<gg, 256, 0, stream>>>(kp, WvT, bv, vt, M, C_DIM, C_DIM);

    attn_kernel<<<dim3(T_SEQ / 16, NH, BATCH), 512, 0, stream>>>(qp, kp, vt, ctx, attn);

    gemm_bt<false, 1><<<gg, 256, 0, stream>>>(ctx, WoT, bo, out, M, C_DIM, C_DIM);
}

// Round 6
// 334.080 us; speedup vs baseline: 1.3665x; 1.3665x over previous
//
#include <hip/hip_runtime.h>

typedef __attribute__((ext_vector_type(8))) short bf16x8;
typedef __attribute__((ext_vector_type(4))) float f32x4;
typedef unsigned short u16;
typedef unsigned int u32;

#define T_SEQ 2048
#define C_DIM 1024
#define NH 16
#define HD 64
#define BATCH 2

__device__ __forceinline__ u16 f2bf(float f) {
    union { float f; u32 u; } v; v.f = f;
    u32 u = v.u;
    u32 r = (u + 0x7FFFu + ((u >> 16) & 1u)) >> 16;
    return (u16)r;
}

__device__ __forceinline__ float fexp2(float x) { return __builtin_amdgcn_exp2f(x); }

// async global->LDS, 16B per lane; LDS dest is wave-uniform base + lane*16
__device__ __forceinline__ void gld_lds16(const void* g, void* l) {
    __builtin_amdgcn_global_load_lds(
        (const __attribute__((address_space(1))) void*)g,
        (__attribute__((address_space(3))) void*)l, 16, 0, 0);
}

// ---------------------------------------------------------------------------
// Transpose 4 weight matrices [C,C] f32 -> [C,C] bf16 (WT[n][k] = W[k][n])
// ---------------------------------------------------------------------------
__global__ __launch_bounds__(256) void transpose_to_bf16(
    const float* __restrict__ W0, const float* __restrict__ W1,
    const float* __restrict__ W2, const float* __restrict__ W3,
    u16* __restrict__ O0, u16* __restrict__ O1,
    u16* __restrict__ O2, u16* __restrict__ O3)
{
    __shared__ float tile[32][33];
    const float* W = blockIdx.z == 0 ? W0 : blockIdx.z == 1 ? W1 : blockIdx.z == 2 ? W2 : W3;
    u16* O = blockIdx.z == 0 ? O0 : blockIdx.z == 1 ? O1 : blockIdx.z == 2 ? O2 : O3;
    const int tx = threadIdx.x, ty = threadIdx.y;
    const int bx = blockIdx.x * 32, by = blockIdx.y * 32;
#pragma unroll
    for (int i = 0; i < 4; ++i)
        tile[ty + i * 8][tx] = W[(size_t)(by + ty + i * 8) * C_DIM + bx + tx];
    __syncthreads();
#pragma unroll
    for (int i = 0; i < 4; ++i)
        O[(size_t)(bx + ty + i * 8) * C_DIM + by + tx] = f2bf(tile[tx][ty + i * 8]);
}

// ---------------------------------------------------------------------------
// GEMM: Y[M,N] = X[M,K] @ W[K,N] + bias, WT[N,K] pre-transposed bf16.
// B staged via global_load_lds(16B); A likewise when X is bf16 (XF32=false),
// else reg-staged with fused f32->bf16.
// OMODE: 0 = bf16 row-major, 1 = f32 row-major, 2 = bf16 per-head V^T
// ---------------------------------------------------------------------------
template<bool XF32, int OMODE>
__global__ __launch_bounds__(256) void gemm_bt(
    const void* __restrict__ Xv, const u16* __restrict__ WT,
    const float* __restrict__ bias, void* __restrict__ Yv,
    int M, int N, int K)
{
    __shared__ u16 As[128 * 32];
    __shared__ u16 Bs[128 * 32];
    const int tid = threadIdx.x;
    const int w = tid >> 6, l = tid & 63;
    const int lr = l & 15, lg = l >> 4;
    const int m0 = blockIdx.y * 128, n0 = blockIdx.x * 128;
    const int wr = (w >> 1) * 64, wc = (w & 1) * 64;
    const int grow = w * 32 + (l >> 2);   // + i*16
    const int gcol = (l & 3) * 8;
    f32x4 acc[4][4] = {};

    for (int k0 = 0; k0 < K; k0 += 32) {
        __syncthreads();
        if (XF32) {
#pragma unroll
            for (int r = 0; r < 2; ++r) {
                const int idx = r * 256 + tid;      // 0..511
                const int row = idx >> 2, cg = idx & 3;
                const float* g = (const float*)Xv + (size_t)(m0 + row) * K + k0 + cg * 8;
                float4 a0 = *(const float4*)g;
                float4 a1 = *(const float4*)(g + 4);
                union { u16 h[8]; uint4 q; } pk;
                pk.h[0] = f2bf(a0.x); pk.h[1] = f2bf(a0.y);
                pk.h[2] = f2bf(a0.z); pk.h[3] = f2bf(a0.w);
                pk.h[4] = f2bf(a1.x); pk.h[5] = f2bf(a1.y);
                pk.h[6] = f2bf(a1.z); pk.h[7] = f2bf(a1.w);
                *(uint4*)&As[row * 32 + cg * 8] = pk.q;
            }
        } else {
#pragma unroll
            for (int i = 0; i < 2; ++i)
                gld_lds16((const u16*)Xv + (size_t)(m0 + grow + i * 16) * K + k0 + gcol,
                          &As[(w * 2 + i) * 512]);
        }
#pragma unroll
        for (int i = 0; i < 2; ++i)
            gld_lds16(WT + (size_t)(n0 + grow + i * 16) * K + k0 + gcol,
                      &Bs[(w * 2 + i) * 512]);
        __syncthreads();
        bf16x8 af[4], bfr[4];
#pragma unroll
        for (int i = 0; i < 4; ++i)
            af[i] = *(const bf16x8*)&As[(wr + i * 16 + lr) * 32 + lg * 8];
#pragma unroll
        for (int j = 0; j < 4; ++j)
            bfr[j] = *(const bf16x8*)&Bs[(wc + j * 16 + lr) * 32 + lg * 8];
#pragma unroll
        for (int i = 0; i < 4; ++i)
#pragma unroll
            for (int j = 0; j < 4; ++j)
                acc[i][j] = __builtin_amdgcn_mfma_f32_16x16x32_bf16(af[i], bfr[j], acc[i][j], 0, 0, 0);
    }

#pragma unroll
    for (int i = 0; i < 4; ++i) {
        const int rowb = m0 + wr + i * 16 + lg * 4;
#pragma unroll
        for (int j = 0; j < 4; ++j) {
            const int col = n0 + wc + j * 16 + lr;
            const float bv = bias[col];
            if (OMODE == 2) {
                union { u16 h[4]; uint2 q; } pk;
#pragma unroll
                for (int r = 0; r < 4; ++r) pk.h[r] = f2bf(acc[i][j][r] + bv);
                const int bb = rowb >> 11, tt = rowb & 2047;
                const int hh = col >> 6, dd = col & 63;
                u16* dst = (u16*)Yv + ((size_t)((bb * NH + hh) * HD + dd)) * T_SEQ + tt;
                *(uint2*)dst = pk.q;
            } else {
#pragma unroll
                for (int r = 0; r < 4; ++r) {
                    const float v = acc[i][j][r] + bv;
                    if (OMODE == 1)
                        ((float*)Yv)[(size_t)(rowb + r) * N + col] = v;
                    else
                        ((u16*)Yv)[(size_t)(rowb + r) * N + col] = f2bf(v);
                }
            }
        }
    }
}

// ---------------------------------------------------------------------------
// Causal attention. Block = (b, h, 16 q-rows), 16 waves (1024 thr) split kv
// in 64-wide tiles (<=2 per wave). Phase A computes S once, caches
// e = exp2(s - m_wave) in registers. Phase B: p = e * scale (no K reload,
// no QK MFMA), nontemporal P stores, shfl-transpose into PV A-frag.
// Grid flattened + XCD-swizzled so each XCD owns 4 consecutive heads.
// ---------------------------------------------------------------------------
#define PV_QS 67                 // float stride per q-row in pvbuf
#define PV_WS (16 * PV_QS + 8)   // float stride per wave block

__global__ __launch_bounds__(1024) void attn_kernel(
    const u16* __restrict__ qp, const u16* __restrict__ kp,
    const u16* __restrict__ vt, u16* __restrict__ ctx,
    float* __restrict__ attn)
{
    __shared__ float statm[16][16], statl[16][16];
    __shared__ float pvbuf[16 * PV_WS];

    const int tid = threadIdx.x;
    const int w = tid >> 6, l = tid & 63;
    const int lr = l & 15, lg = l >> 4;

    // XCD-aware bijective swizzle: 4096 blocks, 8 XCDs, 512 blocks each.
    // Consecutive wgid on one XCD -> strips of one head stay XCD-local.
    const int wgid = (blockIdx.x & 7) * 512 + (blockIdx.x >> 3);
    const int b = wgid >> 11;
    const int h = (wgid >> 7) & 15;
    const int strip = 127 - (wgid & 127);   // heavy-first within XCD chunk
    const int q0 = strip * 16;

    const size_t bh_off = (size_t)b * T_SEQ * C_DIM + h * HD;
    const u16* qb = qp + bh_off;
    const u16* kb = kp + bh_off;
    const u16* vtb = vt + ((size_t)(b * NH + h) * HD) * T_SEQ;
    float* ab = attn + (size_t)(b * NH + h) * T_SEQ * T_SEQ;

    const float SC = 0.125f * 1.44269504088896f;   // 1/sqrt(64) * log2(e)
    const float MNEG = -1e30f;

    const bf16x8 aq0 = *(const bf16x8*)(qb + (size_t)(q0 + lr) * C_DIM + lg * 8);
    const bf16x8 aq1 = *(const bf16x8*)(qb + (size_t)(q0 + lr) * C_DIM + 32 + lg * 8);

    const int qrow = q0 + lr;
    const int n64 = (q0 + 79) >> 6;       // 64-wide kv tiles (kv_end = q0+16)

    // ---- phase A: S once, cache e = exp2(s - m_wave) in registers ----
    f32x4 ec[2][4];
    float ml = MNEG;
#pragma unroll
    for (int tt = 0; tt < 2; ++tt) {
        const int ti = w + 16 * tt;
        if (ti < n64) {
            const int kvb = ti * 64;
            bf16x8 kf[4][2];
#pragma unroll
            for (int t = 0; t < 4; ++t) {
                const u16* kr = kb + (size_t)(kvb + t * 16 + lr) * C_DIM;
                kf[t][0] = *(const bf16x8*)(kr + lg * 8);
                kf[t][1] = *(const bf16x8*)(kr + 32 + lg * 8);
            }
            f32x4 s[4] = {};
#pragma unroll
            for (int t = 0; t < 4; ++t) {
                s[t] = __builtin_amdgcn_mfma_f32_16x16x32_bf16(kf[t][0], aq0, s[t], 0, 0, 0);
                s[t] = __builtin_amdgcn_mfma_f32_16x16x32_bf16(kf[t][1], aq1, s[t], 0, 0, 0);
            }
#pragma unroll
            for (int t = 0; t < 4; ++t)
#pragma unroll
                for (int r = 0; r < 4; ++r) {
                    float v = s[t][r] * SC;
                    if (kvb + 16 * t + 4 * lg + r > qrow) v = MNEG;
                    ec[tt][t][r] = v;
                    ml = fmaxf(ml, v);
                }
        } else {
#pragma unroll
            for (int t = 0; t < 4; ++t)
#pragma unroll
                for (int r = 0; r < 4; ++r) ec[tt][t][r] = MNEG;
        }
    }
    ml = fmaxf(ml, __shfl_xor(ml, 16));
    ml = fmaxf(ml, __shfl_xor(ml, 32));
    float ll = 0.f;
#pragma unroll
    for (int tt = 0; tt < 2; ++tt)
#pragma unroll
        for (int t = 0; t < 4; ++t)
#pragma unroll
            for (int r = 0; r < 4; ++r) {
                const float e = fexp2(ec[tt][t][r] - ml);
                ec[tt][t][r] = e;
                ll += e;
            }
    ll += __shfl_xor(ll, 16);
    ll += __shfl_xor(ll, 32);
    if (l < 16) { statm[w][lr] = ml; statl[w][lr] = ll; }
    __syncthreads();

    float mf = MNEG;
#pragma unroll
    for (int ww = 0; ww < 16; ++ww) mf = fmaxf(mf, statm[ww][lr]);
    float lf = 0.f;
#pragma unroll
    for (int ww = 0; ww < 16; ++ww) lf += statl[ww][lr] * fexp2(statm[ww][lr] - mf);
    // p = e * exp2(ml - mf) / lf ; for waves with no valid data scale = 0
    const float scale = fexp2(ml - mf) / lf;

    // ---- phase B: P stores + PV from cached e (no K reload / QK MFMA) ----
    f32x4 cacc[4] = {};
#pragma unroll
    for (int tt = 0; tt < 2; ++tt) {
        const int ti = w + 16 * tt;
        if (ti < n64) {
            const int kvb = ti * 64;
            bf16x8 vf[2][4];
#pragma unroll
            for (int st = 0; st < 2; ++st)
#pragma unroll
                for (int dt = 0; dt < 4; ++dt)
                    vf[st][dt] = *(const bf16x8*)(vtb + (size_t)(dt * 16 + lr) * T_SEQ
                                                  + kvb + st * 32 + lg * 8);
#pragma unroll
            for (int st = 0; st < 2; ++st) {
                u32 pw[2][2];
#pragma unroll
                for (int t2 = 0; t2 < 2; ++t2) {
                    const int t = st * 2 + t2;
                    float p[4];
#pragma unroll
                    for (int r = 0; r < 4; ++r) p[r] = ec[tt][t][r] * scale;
                    f32x4 pv4 = { p[0], p[1], p[2], p[3] };
                    __builtin_nontemporal_store(pv4,
                        (f32x4*)(ab + (size_t)qrow * T_SEQ + kvb + 16 * t + 4 * lg));
                    pw[t2][0] = (u32)f2bf(p[0]) | ((u32)f2bf(p[1]) << 16);
                    pw[t2][1] = (u32)f2bf(p[2]) | ((u32)f2bf(p[3]) << 16);
                }
                // shuffle-transpose: C-layout (kv in lg-groups of 4) -> A-frag (kv=8*lg+j)
                const int bl = lr + ((lg & 1) << 5);
                const u32 a0 = (u32)__shfl((int)pw[0][0], bl);
                const u32 a1 = (u32)__shfl((int)pw[0][1], bl);
                const u32 a2 = (u32)__shfl((int)pw[0][0], bl + 16);
                const u32 a3 = (u32)__shfl((int)pw[0][1], bl + 16);
                const u32 b0 = (u32)__shfl((int)pw[1][0], bl);
                const u32 b1 = (u32)__shfl((int)pw[1][1], bl);
                const u32 b2 = (u32)__shfl((int)pw[1][0], bl + 16);
                const u32 b3 = (u32)__shfl((int)pw[1][1], bl + 16);
                const bool hi2 = lg >= 2;
                union { u32 ww[4]; bf16x8 v; } pa;
                pa.ww[0] = hi2 ? b0 : a0;
                pa.ww[1] = hi2 ? b1 : a1;
                pa.ww[2] = hi2 ? b2 : a2;
                pa.ww[3] = hi2 ? b3 : a3;
#pragma unroll
                for (int dt = 0; dt < 4; ++dt)
                    cacc[dt] = __builtin_amdgcn_mfma_f32_16x16x32_bf16(pa.v, vf[st][dt], cacc[dt], 0, 0, 0);
            }
        }
    }

    // dump PV partials (cacc[dt][r] = ctx[q=4*lg+r][d=dt*16+lr])
    {
        float* pwv = pvbuf + w * PV_WS;
#pragma unroll
        for (int dt = 0; dt < 4; ++dt)
#pragma unroll
            for (int r = 0; r < 4; ++r)
                pwv[(4 * lg + r) * PV_QS + dt * 16 + lr] = cacc[dt][r];
    }
    __syncthreads();

    // reduce PV across 16 waves + write ctx (bf16): 1024 elems, 1 per thread
    {
        const int qq = tid >> 6;            // 0..15
        const int d0 = tid & 63;            // 0..63
        float s0 = 0.f;
#pragma unroll
        for (int ww = 0; ww < 16; ++ww)
            s0 += pvbuf[ww * PV_WS + qq * PV_QS + d0];
        u16* cb = ctx + bh_off;
        cb[(size_t)(q0 + qq) * C_DIM + d0] = f2bf(s0);
    }

    // zero-fill [n64*64, T) for all 16 rows (nontemporal streaming stores)
    {
        const int zs = n64 * 64;
        const int row = tid >> 6;
        const int c0 = (tid & 63) * 4;
        float* zr = ab + (size_t)(q0 + row) * T_SEQ;
        const f32x4 z4 = { 0.f, 0.f, 0.f, 0.f };
        for (int c = zs + c0; c < T_SEQ; c += 256)
            __builtin_nontemporal_store(z4, (f32x4*)(zr + c));
    }
}

// ---------------------------------------------------------------------------
extern "C" void kernel_launch(void* const* d_in, const int* in_sizes, int n_in,
                              void* d_out, int out_size, void* d_ws, size_t ws_size,
                              hipStream_t stream)
{
    const float* q  = (const float*)d_in[0];
    const float* k  = (const float*)d_in[1];
    const float* Wq = (const float*)d_in[2];
    const float* bq = (const float*)d_in[3];
    const float* Wk = (const float*)d_in[4];
    const float* bk = (const float*)d_in[5];
    const float* Wv = (const float*)d_in[6];
    const float* bv = (const float*)d_in[7];
    const float* Wo = (const float*)d_in[8];
    const float* bo = (const float*)d_in[9];
    (void)in_sizes; (void)n_in; (void)out_size; (void)ws_size;

    float* out = (float*)d_out;
    float* attn = out + (size_t)BATCH * T_SEQ * C_DIM;

    const size_t MC = (size_t)BATCH * T_SEQ * C_DIM;   // 4,194,304 elems
    u16* qp  = (u16*)d_ws;
    u16* kp  = qp + MC;
    u16* vt  = kp + MC;          // V^T: [B][H][D][T]
    u16* ctx = vt + MC;
    u16* WqT = ctx + MC;
    u16* WkT = WqT + (size_t)C_DIM * C_DIM;
    u16* WvT = WkT + (size_t)C_DIM * C_DIM;
    u16* WoT = WvT + (size_t)C_DIM * C_DIM;

    transpose_to_bf16<<<dim3(32, 32, 4), dim3(32, 8), 0, stream>>>(
        Wq, Wk, Wv, Wo, WqT, WkT, WvT, WoT);

    const int M = BATCH * T_SEQ;
    dim3 gg(C_DIM / 128, M / 128);
    gemm_bt<true,  0><<<gg, 256, 0, stream>>>(q,  WqT, bq, qp, M, C_DIM, C_DIM);
    gemm_bt<true,  0><<<gg, 256, 0, stream>>>(k,  WkT, bk, kp, M, C_DIM, C_DIM);
    gemm_bt<false, 2><<<gg, 256, 0, stream>>>(kp, WvT, bv, vt, M, C_DIM, C_DIM);

    attn_kernel<<<dim3(4096), 1024, 0, stream>>>(qp, kp, vt, ctx, attn);

    gemm_bt<false, 1><<<gg, 256, 0, stream>>>(ctx, WoT, bo, out, M, C_DIM, C_DIM);
}

// Round 7
// 295.624 us; speedup vs baseline: 1.5442x; 1.1301x over previous
//
#include <hip/hip_runtime.h>

typedef __attribute__((ext_vector_type(8))) short bf16x8;
typedef __attribute__((ext_vector_type(4))) float f32x4;
typedef unsigned short u16;
typedef unsigned int u32;

#define T_SEQ 2048
#define C_DIM 1024
#define NH 16
#define HD 64
#define BATCH 2

__device__ __forceinline__ u16 f2bf(float f) {
    union { float f; u32 u; } v; v.f = f;
    u32 u = v.u;
    u32 r = (u + 0x7FFFu + ((u >> 16) & 1u)) >> 16;
    return (u16)r;
}

__device__ __forceinline__ float fexp2(float x) { return __builtin_amdgcn_exp2f(x); }

// async global->LDS, 16B per lane; LDS dest is wave-uniform base + lane*16
__device__ __forceinline__ void gld_lds16(const void* g, void* l) {
    __builtin_amdgcn_global_load_lds(
        (const __attribute__((address_space(1))) void*)g,
        (__attribute__((address_space(3))) void*)l, 16, 0, 0);
}

// ---------------------------------------------------------------------------
// Transpose 4 weight matrices [C,C] f32 -> [C,C] bf16 (WT[n][k] = W[k][n])
// ---------------------------------------------------------------------------
__global__ __launch_bounds__(256) void transpose_to_bf16(
    const float* __restrict__ W0, const float* __restrict__ W1,
    const float* __restrict__ W2, const float* __restrict__ W3,
    u16* __restrict__ O0, u16* __restrict__ O1,
    u16* __restrict__ O2, u16* __restrict__ O3)
{
    __shared__ float tile[32][33];
    const float* W = blockIdx.z == 0 ? W0 : blockIdx.z == 1 ? W1 : blockIdx.z == 2 ? W2 : W3;
    u16* O = blockIdx.z == 0 ? O0 : blockIdx.z == 1 ? O1 : blockIdx.z == 2 ? O2 : O3;
    const int tx = threadIdx.x, ty = threadIdx.y;
    const int bx = blockIdx.x * 32, by = blockIdx.y * 32;
#pragma unroll
    for (int i = 0; i < 4; ++i)
        tile[ty + i * 8][tx] = W[(size_t)(by + ty + i * 8) * C_DIM + bx + tx];
    __syncthreads();
#pragma unroll
    for (int i = 0; i < 4; ++i)
        O[(size_t)(bx + ty + i * 8) * C_DIM + by + tx] = f2bf(tile[tx][ty + i * 8]);
}

// ---------------------------------------------------------------------------
// GEMM: Y[M,N] = X[M,K] @ W[K,N] + bias, WT[N,K] pre-transposed bf16.
// 64x128 (MxN) tile, BK=32, 4 waves (each 64 rows x 32 cols, acc 4x2).
// Grid (N/128, M/64, nz); blockIdx.z selects pointer set (q/k fusion).
// OMODE: 0 = bf16 row-major, 1 = f32 row-major, 2 = bf16 per-head V^T
// ---------------------------------------------------------------------------
template<bool XF32, int OMODE>
__global__ __launch_bounds__(256) void gemm_bt(
    const void* __restrict__ X0_, const void* __restrict__ X1_,
    const u16* __restrict__ W0T, const u16* __restrict__ W1T,
    const float* __restrict__ b0_, const float* __restrict__ b1_,
    void* __restrict__ Y0_, void* __restrict__ Y1_,
    int M, int N, int K)
{
    __shared__ u16 As[64 * 32];
    __shared__ u16 Bs[128 * 32];
    const int tid = threadIdx.x;
    const int w = tid >> 6, l = tid & 63;
    const int lr = l & 15, lg = l >> 4;
    const int z = blockIdx.z;
    const void* Xv = z ? X1_ : X0_;
    const u16* WT = z ? W1T : W0T;
    const float* bias = z ? b1_ : b0_;
    void* Yv = z ? Y1_ : Y0_;
    const int m0 = blockIdx.y * 64, n0 = blockIdx.x * 128;
    const int grow = l >> 2, gcol = (l & 3) * 8;
    f32x4 acc[4][2] = {};

    for (int k0 = 0; k0 < K; k0 += 32) {
        __syncthreads();
        if (XF32) {
            // 256 threads stage A: 64 rows x 32 cols (f32 -> bf16)
            const int row = tid >> 2, cg = tid & 3;
            const float* g = (const float*)Xv + (size_t)(m0 + row) * K + k0 + cg * 8;
            float4 a0 = *(const float4*)g;
            float4 a1 = *(const float4*)(g + 4);
            union { u16 h[8]; uint4 q; } pk;
            pk.h[0] = f2bf(a0.x); pk.h[1] = f2bf(a0.y);
            pk.h[2] = f2bf(a0.z); pk.h[3] = f2bf(a0.w);
            pk.h[4] = f2bf(a1.x); pk.h[5] = f2bf(a1.y);
            pk.h[6] = f2bf(a1.z); pk.h[7] = f2bf(a1.w);
            *(uint4*)&As[row * 32 + cg * 8] = pk.q;
        } else {
            // wave w stages A rows [w*16, w*16+16)
            gld_lds16((const u16*)Xv + (size_t)(m0 + w * 16 + grow) * K + k0 + gcol,
                      &As[w * 512]);
        }
        // wave w stages B rows [w*32, w*32+32) in 2 insts
#pragma unroll
        for (int i = 0; i < 2; ++i)
            gld_lds16(WT + (size_t)(n0 + w * 32 + i * 16 + grow) * K + k0 + gcol,
                      &Bs[(w * 2 + i) * 512]);
        __syncthreads();
        bf16x8 af[4], bfr[2];
#pragma unroll
        for (int i = 0; i < 4; ++i)
            af[i] = *(const bf16x8*)&As[(i * 16 + lr) * 32 + lg * 8];
#pragma unroll
        for (int j = 0; j < 2; ++j)
            bfr[j] = *(const bf16x8*)&Bs[(w * 32 + j * 16 + lr) * 32 + lg * 8];
#pragma unroll
        for (int i = 0; i < 4; ++i)
#pragma unroll
            for (int j = 0; j < 2; ++j)
                acc[i][j] = __builtin_amdgcn_mfma_f32_16x16x32_bf16(af[i], bfr[j], acc[i][j], 0, 0, 0);
    }

#pragma unroll
    for (int i = 0; i < 4; ++i) {
        const int rowb = m0 + i * 16 + lg * 4;
#pragma unroll
        for (int j = 0; j < 2; ++j) {
            const int col = n0 + w * 32 + j * 16 + lr;
            const float bv = bias[col];
            if (OMODE == 2) {
                union { u16 h[4]; uint2 q; } pk;
#pragma unroll
                for (int r = 0; r < 4; ++r) pk.h[r] = f2bf(acc[i][j][r] + bv);
                const int bb = rowb >> 11, tt = rowb & 2047;
                const int hh = col >> 6, dd = col & 63;
                u16* dst = (u16*)Yv + ((size_t)((bb * NH + hh) * HD + dd)) * T_SEQ + tt;
                *(uint2*)dst = pk.q;
            } else {
#pragma unroll
                for (int r = 0; r < 4; ++r) {
                    const float v = acc[i][j][r] + bv;
                    if (OMODE == 1)
                        ((float*)Yv)[(size_t)(rowb + r) * N + col] = v;
                    else
                        ((u16*)Yv)[(size_t)(rowb + r) * N + col] = f2bf(v);
                }
            }
        }
    }
}

// ---------------------------------------------------------------------------
// Causal attention. Block = (b, h, 16 q-rows), 16 waves (1024 thr) split kv
// in 64-wide tiles (<=2 per wave). Phase A computes S once, caches
// e = exp2(s - m_wave) in registers. Phase B: p = e * scale (no K reload,
// no QK MFMA), nontemporal P stores, shfl-transpose into PV A-frag.
// Grid flattened + XCD-swizzled so each XCD owns 4 consecutive heads.
// ---------------------------------------------------------------------------
#define PV_QS 67                 // float stride per q-row in pvbuf
#define PV_WS (16 * PV_QS + 8)   // float stride per wave block

__global__ __launch_bounds__(1024) void attn_kernel(
    const u16* __restrict__ qp, const u16* __restrict__ kp,
    const u16* __restrict__ vt, u16* __restrict__ ctx,
    float* __restrict__ attn)
{
    __shared__ float statm[16][16], statl[16][16];
    __shared__ float pvbuf[16 * PV_WS];

    const int tid = threadIdx.x;
    const int w = tid >> 6, l = tid & 63;
    const int lr = l & 15, lg = l >> 4;

    // XCD-aware bijective swizzle: 4096 blocks, 8 XCDs, 512 blocks each.
    const int wgid = (blockIdx.x & 7) * 512 + (blockIdx.x >> 3);
    const int b = wgid >> 11;
    const int h = (wgid >> 7) & 15;
    const int strip = 127 - (wgid & 127);   // heavy-first within XCD chunk
    const int q0 = strip * 16;

    const size_t bh_off = (size_t)b * T_SEQ * C_DIM + h * HD;
    const u16* qb = qp + bh_off;
    const u16* kb = kp + bh_off;
    const u16* vtb = vt + ((size_t)(b * NH + h) * HD) * T_SEQ;
    float* ab = attn + (size_t)(b * NH + h) * T_SEQ * T_SEQ;

    const float SC = 0.125f * 1.44269504088896f;   // 1/sqrt(64) * log2(e)
    const float MNEG = -1e30f;

    const bf16x8 aq0 = *(const bf16x8*)(qb + (size_t)(q0 + lr) * C_DIM + lg * 8);
    const bf16x8 aq1 = *(const bf16x8*)(qb + (size_t)(q0 + lr) * C_DIM + 32 + lg * 8);

    const int qrow = q0 + lr;
    const int n64 = (q0 + 79) >> 6;       // 64-wide kv tiles (kv_end = q0+16)

    // ---- phase A: S once, cache e = exp2(s - m_wave) in registers ----
    f32x4 ec[2][4];
    float ml = MNEG;
#pragma unroll
    for (int tt = 0; tt < 2; ++tt) {
        const int ti = w + 16 * tt;
        if (ti < n64) {
            const int kvb = ti * 64;
            bf16x8 kf[4][2];
#pragma unroll
            for (int t = 0; t < 4; ++t) {
                const u16* kr = kb + (size_t)(kvb + t * 16 + lr) * C_DIM;
                kf[t][0] = *(const bf16x8*)(kr + lg * 8);
                kf[t][1] = *(const bf16x8*)(kr + 32 + lg * 8);
            }
            f32x4 s[4] = {};
#pragma unroll
            for (int t = 0; t < 4; ++t) {
                s[t] = __builtin_amdgcn_mfma_f32_16x16x32_bf16(kf[t][0], aq0, s[t], 0, 0, 0);
                s[t] = __builtin_amdgcn_mfma_f32_16x16x32_bf16(kf[t][1], aq1, s[t], 0, 0, 0);
            }
#pragma unroll
            for (int t = 0; t < 4; ++t)
#pragma unroll
                for (int r = 0; r < 4; ++r) {
                    float v = s[t][r] * SC;
                    if (kvb + 16 * t + 4 * lg + r > qrow) v = MNEG;
                    ec[tt][t][r] = v;
                    ml = fmaxf(ml, v);
                }
        } else {
#pragma unroll
            for (int t = 0; t < 4; ++t)
#pragma unroll
                for (int r = 0; r < 4; ++r) ec[tt][t][r] = MNEG;
        }
    }
    ml = fmaxf(ml, __shfl_xor(ml, 16));
    ml = fmaxf(ml, __shfl_xor(ml, 32));
    float ll = 0.f;
#pragma unroll
    for (int tt = 0; tt < 2; ++tt)
#pragma unroll
        for (int t = 0; t < 4; ++t)
#pragma unroll
            for (int r = 0; r < 4; ++r) {
                const float e = fexp2(ec[tt][t][r] - ml);
                ec[tt][t][r] = e;
                ll += e;
            }
    ll += __shfl_xor(ll, 16);
    ll += __shfl_xor(ll, 32);
    if (l < 16) { statm[w][lr] = ml; statl[w][lr] = ll; }
    __syncthreads();

    float mf = MNEG;
#pragma unroll
    for (int ww = 0; ww < 16; ++ww) mf = fmaxf(mf, statm[ww][lr]);
    float lf = 0.f;
#pragma unroll
    for (int ww = 0; ww < 16; ++ww) lf += statl[ww][lr] * fexp2(statm[ww][lr] - mf);
    const float scale = fexp2(ml - mf) / lf;

    // ---- phase B: P stores + PV from cached e (no K reload / QK MFMA) ----
    f32x4 cacc[4] = {};
#pragma unroll
    for (int tt = 0; tt < 2; ++tt) {
        const int ti = w + 16 * tt;
        if (ti < n64) {
            const int kvb = ti * 64;
            bf16x8 vf[2][4];
#pragma unroll
            for (int st = 0; st < 2; ++st)
#pragma unroll
                for (int dt = 0; dt < 4; ++dt)
                    vf[st][dt] = *(const bf16x8*)(vtb + (size_t)(dt * 16 + lr) * T_SEQ
                                                  + kvb + st * 32 + lg * 8);
#pragma unroll
            for (int st = 0; st < 2; ++st) {
                u32 pw[2][2];
#pragma unroll
                for (int t2 = 0; t2 < 2; ++t2) {
                    const int t = st * 2 + t2;
                    float p[4];
#pragma unroll
                    for (int r = 0; r < 4; ++r) p[r] = ec[tt][t][r] * scale;
                    f32x4 pv4 = { p[0], p[1], p[2], p[3] };
                    __builtin_nontemporal_store(pv4,
                        (f32x4*)(ab + (size_t)qrow * T_SEQ + kvb + 16 * t + 4 * lg));
                    pw[t2][0] = (u32)f2bf(p[0]) | ((u32)f2bf(p[1]) << 16);
                    pw[t2][1] = (u32)f2bf(p[2]) | ((u32)f2bf(p[3]) << 16);
                }
                // shuffle-transpose: C-layout (kv in lg-groups of 4) -> A-frag (kv=8*lg+j)
                const int bl = lr + ((lg & 1) << 5);
                const u32 a0 = (u32)__shfl((int)pw[0][0], bl);
                const u32 a1 = (u32)__shfl((int)pw[0][1], bl);
                const u32 a2 = (u32)__shfl((int)pw[0][0], bl + 16);
                const u32 a3 = (u32)__shfl((int)pw[0][1], bl + 16);
                const u32 b0 = (u32)__shfl((int)pw[1][0], bl);
                const u32 b1 = (u32)__shfl((int)pw[1][1], bl);
                const u32 b2 = (u32)__shfl((int)pw[1][0], bl + 16);
                const u32 b3 = (u32)__shfl((int)pw[1][1], bl + 16);
                const bool hi2 = lg >= 2;
                union { u32 ww[4]; bf16x8 v; } pa;
                pa.ww[0] = hi2 ? b0 : a0;
                pa.ww[1] = hi2 ? b1 : a1;
                pa.ww[2] = hi2 ? b2 : a2;
                pa.ww[3] = hi2 ? b3 : a3;
#pragma unroll
                for (int dt = 0; dt < 4; ++dt)
                    cacc[dt] = __builtin_amdgcn_mfma_f32_16x16x32_bf16(pa.v, vf[st][dt], cacc[dt], 0, 0, 0);
            }
        }
    }

    // dump PV partials (cacc[dt][r] = ctx[q=4*lg+r][d=dt*16+lr])
    {
        float* pwv = pvbuf + w * PV_WS;
#pragma unroll
        for (int dt = 0; dt < 4; ++dt)
#pragma unroll
            for (int r = 0; r < 4; ++r)
                pwv[(4 * lg + r) * PV_QS + dt * 16 + lr] = cacc[dt][r];
    }
    __syncthreads();

    // reduce PV across 16 waves + write ctx (bf16): 1024 elems, 1 per thread
    {
        const int qq = tid >> 6;            // 0..15
        const int d0 = tid & 63;            // 0..63
        float s0 = 0.f;
#pragma unroll
        for (int ww = 0; ww < 16; ++ww)
            s0 += pvbuf[ww * PV_WS + qq * PV_QS + d0];
        u16* cb = ctx + bh_off;
        cb[(size_t)(q0 + qq) * C_DIM + d0] = f2bf(s0);
    }

    // zero-fill [n64*64, T) for all 16 rows (nontemporal streaming stores)
    {
        const int zs = n64 * 64;
        const int row = tid >> 6;
        const int c0 = (tid & 63) * 4;
        float* zr = ab + (size_t)(q0 + row) * T_SEQ;
        const f32x4 z4 = { 0.f, 0.f, 0.f, 0.f };
        for (int c = zs + c0; c < T_SEQ; c += 256)
            __builtin_nontemporal_store(z4, (f32x4*)(zr + c));
    }
}

// ---------------------------------------------------------------------------
extern "C" void kernel_launch(void* const* d_in, const int* in_sizes, int n_in,
                              void* d_out, int out_size, void* d_ws, size_t ws_size,
                              hipStream_t stream)
{
    const float* q  = (const float*)d_in[0];
    const float* k  = (const float*)d_in[1];
    const float* Wq = (const float*)d_in[2];
    const float* bq = (const float*)d_in[3];
    const float* Wk = (const float*)d_in[4];
    const float* bk = (const float*)d_in[5];
    const float* Wv = (const float*)d_in[6];
    const float* bv = (const float*)d_in[7];
    const float* Wo = (const float*)d_in[8];
    const float* bo = (const float*)d_in[9];
    (void)in_sizes; (void)n_in; (void)out_size; (void)ws_size;

    float* out = (float*)d_out;
    float* attn = out + (size_t)BATCH * T_SEQ * C_DIM;

    const size_t MC = (size_t)BATCH * T_SEQ * C_DIM;   // 4,194,304 elems
    u16* qp  = (u16*)d_ws;
    u16* kp  = qp + MC;
    u16* vt  = kp + MC;          // V^T: [B][H][D][T]
    u16* ctx = vt + MC;
    u16* WqT = ctx + MC;
    u16* WkT = WqT + (size_t)C_DIM * C_DIM;
    u16* WvT = WkT + (size_t)C_DIM * C_DIM;
    u16* WoT = WvT + (size_t)C_DIM * C_DIM;

    transpose_to_bf16<<<dim3(32, 32, 4), dim3(32, 8), 0, stream>>>(
        Wq, Wk, Wv, Wo, WqT, WkT, WvT, WoT);

    const int M = BATCH * T_SEQ;
    dim3 gqk(C_DIM / 128, M / 64, 2);
    dim3 g1(C_DIM / 128, M / 64, 1);
    // fused q & k projections (z selects pointer set)
    gemm_bt<true, 0><<<gqk, 256, 0, stream>>>(q, k, WqT, WkT, bq, bk,
                                              qp, kp, M, C_DIM, C_DIM);
    // vp = kp @ Wv -> V^T layout
    gemm_bt<false, 2><<<g1, 256, 0, stream>>>(kp, kp, WvT, WvT, bv, bv,
                                              vt, vt, M, C_DIM, C_DIM);

    attn_kernel<<<dim3(4096), 1024, 0, stream>>>(qp, kp, vt, ctx, attn);

    // out = ctx @ Wo (f32)
    gemm_bt<false, 1><<<g1, 256, 0, stream>>>(ctx, ctx, WoT, WoT, bo, bo,
                                              out, out, M, C_DIM, C_DIM);
}

// Round 8
// 287.893 us; speedup vs baseline: 1.5857x; 1.0269x over previous
//
#include <hip/hip_runtime.h>

typedef __attribute__((ext_vector_type(8))) short bf16x8;
typedef __attribute__((ext_vector_type(4))) float f32x4;
typedef unsigned short u16;
typedef unsigned int u32;

#define T_SEQ 2048
#define C_DIM 1024
#define NH 16
#define HD 64
#define BATCH 2

__device__ __forceinline__ u16 f2bf(float f) {
    union { float f; u32 u; } v; v.f = f;
    u32 u = v.u;
    u32 r = (u + 0x7FFFu + ((u >> 16) & 1u)) >> 16;
    return (u16)r;
}

__device__ __forceinline__ float fexp2(float x) { return __builtin_amdgcn_exp2f(x); }

// async global->LDS, 16B per lane; LDS dest is wave-uniform base + lane*16
__device__ __forceinline__ void gld_lds16(const void* g, void* l) {
    __builtin_amdgcn_global_load_lds(
        (const __attribute__((address_space(1))) void*)g,
        (__attribute__((address_space(3))) void*)l, 16, 0, 0);
}

// ---------------------------------------------------------------------------
// Transpose 4 weight matrices [C,C] f32 -> [C,C] bf16 (WT[n][k] = W[k][n])
// ---------------------------------------------------------------------------
__global__ __launch_bounds__(256) void transpose_to_bf16(
    const float* __restrict__ W0, const float* __restrict__ W1,
    const float* __restrict__ W2, const float* __restrict__ W3,
    u16* __restrict__ O0, u16* __restrict__ O1,
    u16* __restrict__ O2, u16* __restrict__ O3)
{
    __shared__ float tile[32][33];
    const float* W = blockIdx.z == 0 ? W0 : blockIdx.z == 1 ? W1 : blockIdx.z == 2 ? W2 : W3;
    u16* O = blockIdx.z == 0 ? O0 : blockIdx.z == 1 ? O1 : blockIdx.z == 2 ? O2 : O3;
    const int tx = threadIdx.x, ty = threadIdx.y;
    const int bx = blockIdx.x * 32, by = blockIdx.y * 32;
#pragma unroll
    for (int i = 0; i < 4; ++i)
        tile[ty + i * 8][tx] = W[(size_t)(by + ty + i * 8) * C_DIM + bx + tx];
    __syncthreads();
#pragma unroll
    for (int i = 0; i < 4; ++i)
        O[(size_t)(bx + ty + i * 8) * C_DIM + by + tx] = f2bf(tile[tx][ty + i * 8]);
}

// ---------------------------------------------------------------------------
// GEMM: Y[M,N] = X[M,K] @ W[K,N] + bias, WT[N,K] pre-transposed bf16.
// 64x128 (MxN) tile, BK=32, 4 waves (each 64 rows x 32 cols, acc 4x2).
// Grid (N/128, M/64, nz); blockIdx.z selects pointer set (q/k fusion).
// OMODE: 0 = bf16 row-major, 1 = f32 row-major, 2 = bf16 per-head V^T
// ---------------------------------------------------------------------------
template<bool XF32, int OMODE>
__global__ __launch_bounds__(256) void gemm_bt(
    const void* __restrict__ X0_, const void* __restrict__ X1_,
    const u16* __restrict__ W0T, const u16* __restrict__ W1T,
    const float* __restrict__ b0_, const float* __restrict__ b1_,
    void* __restrict__ Y0_, void* __restrict__ Y1_,
    int M, int N, int K)
{
    __shared__ u16 As[64 * 32];
    __shared__ u16 Bs[128 * 32];
    const int tid = threadIdx.x;
    const int w = tid >> 6, l = tid & 63;
    const int lr = l & 15, lg = l >> 4;
    const int z = blockIdx.z;
    const void* Xv = z ? X1_ : X0_;
    const u16* WT = z ? W1T : W0T;
    const float* bias = z ? b1_ : b0_;
    void* Yv = z ? Y1_ : Y0_;
    const int m0 = blockIdx.y * 64, n0 = blockIdx.x * 128;
    const int grow = l >> 2, gcol = (l & 3) * 8;
    f32x4 acc[4][2] = {};

    for (int k0 = 0; k0 < K; k0 += 32) {
        __syncthreads();
        if (XF32) {
            // 256 threads stage A: 64 rows x 32 cols (f32 -> bf16)
            const int row = tid >> 2, cg = tid & 3;
            const float* g = (const float*)Xv + (size_t)(m0 + row) * K + k0 + cg * 8;
            float4 a0 = *(const float4*)g;
            float4 a1 = *(const float4*)(g + 4);
            union { u16 h[8]; uint4 q; } pk;
            pk.h[0] = f2bf(a0.x); pk.h[1] = f2bf(a0.y);
            pk.h[2] = f2bf(a0.z); pk.h[3] = f2bf(a0.w);
            pk.h[4] = f2bf(a1.x); pk.h[5] = f2bf(a1.y);
            pk.h[6] = f2bf(a1.z); pk.h[7] = f2bf(a1.w);
            *(uint4*)&As[row * 32 + cg * 8] = pk.q;
        } else {
            // wave w stages A rows [w*16, w*16+16)
            gld_lds16((const u16*)Xv + (size_t)(m0 + w * 16 + grow) * K + k0 + gcol,
                      &As[w * 512]);
        }
        // wave w stages B rows [w*32, w*32+32) in 2 insts
#pragma unroll
        for (int i = 0; i < 2; ++i)
            gld_lds16(WT + (size_t)(n0 + w * 32 + i * 16 + grow) * K + k0 + gcol,
                      &Bs[(w * 2 + i) * 512]);
        __syncthreads();
        bf16x8 af[4], bfr[2];
#pragma unroll
        for (int i = 0; i < 4; ++i)
            af[i] = *(const bf16x8*)&As[(i * 16 + lr) * 32 + lg * 8];
#pragma unroll
        for (int j = 0; j < 2; ++j)
            bfr[j] = *(const bf16x8*)&Bs[(w * 32 + j * 16 + lr) * 32 + lg * 8];
#pragma unroll
        for (int i = 0; i < 4; ++i)
#pragma unroll
            for (int j = 0; j < 2; ++j)
                acc[i][j] = __builtin_amdgcn_mfma_f32_16x16x32_bf16(af[i], bfr[j], acc[i][j], 0, 0, 0);
    }

#pragma unroll
    for (int i = 0; i < 4; ++i) {
        const int rowb = m0 + i * 16 + lg * 4;
#pragma unroll
        for (int j = 0; j < 2; ++j) {
            const int col = n0 + w * 32 + j * 16 + lr;
            const float bv = bias[col];
            if (OMODE == 2) {
                union { u16 h[4]; uint2 q; } pk;
#pragma unroll
                for (int r = 0; r < 4; ++r) pk.h[r] = f2bf(acc[i][j][r] + bv);
                const int bb = rowb >> 11, tt = rowb & 2047;
                const int hh = col >> 6, dd = col & 63;
                u16* dst = (u16*)Yv + ((size_t)((bb * NH + hh) * HD + dd)) * T_SEQ + tt;
                *(uint2*)dst = pk.q;
            } else {
#pragma unroll
                for (int r = 0; r < 4; ++r) {
                    const float v = acc[i][j][r] + bv;
                    if (OMODE == 1)
                        ((float*)Yv)[(size_t)(rowb + r) * N + col] = v;
                    else
                        ((u16*)Yv)[(size_t)(rowb + r) * N + col] = f2bf(v);
                }
            }
        }
    }
}

// ---------------------------------------------------------------------------
// Causal attention. Block = (b, h, 16 q-rows), 16 waves (1024 thr).
// kv split in 32-wide tiles, up to 4 per wave (ti = w + 16*j) -> balanced.
// Phase A computes S once, caches e = exp2(s - m_wave) in registers.
// Phase B: p = e * scale, nontemporal P stores, shfl-transpose into PV A-frag,
// setprio(1) around the PV MFMA cluster.
// Grid flattened + XCD-swizzled so each XCD owns 4 consecutive heads.
// ---------------------------------------------------------------------------
#define PV_QS 67                 // float stride per q-row in pvbuf
#define PV_WS (16 * PV_QS + 8)   // float stride per wave block

__global__ __launch_bounds__(1024) void attn_kernel(
    const u16* __restrict__ qp, const u16* __restrict__ kp,
    const u16* __restrict__ vt, u16* __restrict__ ctx,
    float* __restrict__ attn)
{
    __shared__ float statm[16][16], statl[16][16];
    __shared__ float pvbuf[16 * PV_WS];

    const int tid = threadIdx.x;
    const int w = tid >> 6, l = tid & 63;
    const int lr = l & 15, lg = l >> 4;

    // XCD-aware bijective swizzle: 4096 blocks, 8 XCDs, 512 blocks each.
    const int wgid = (blockIdx.x & 7) * 512 + (blockIdx.x >> 3);
    const int b = wgid >> 11;
    const int h = (wgid >> 7) & 15;
    const int strip = 127 - (wgid & 127);   // heavy-first within XCD chunk
    const int q0 = strip * 16;

    const size_t bh_off = (size_t)b * T_SEQ * C_DIM + h * HD;
    const u16* qb = qp + bh_off;
    const u16* kb = kp + bh_off;
    const u16* vtb = vt + ((size_t)(b * NH + h) * HD) * T_SEQ;
    float* ab = attn + (size_t)(b * NH + h) * T_SEQ * T_SEQ;

    const float SC = 0.125f * 1.44269504088896f;   // 1/sqrt(64) * log2(e)
    const float MNEG = -1e30f;

    const bf16x8 aq0 = *(const bf16x8*)(qb + (size_t)(q0 + lr) * C_DIM + lg * 8);
    const bf16x8 aq1 = *(const bf16x8*)(qb + (size_t)(q0 + lr) * C_DIM + 32 + lg * 8);

    const int qrow = q0 + lr;
    const int n32 = (q0 + 47) >> 5;       // 32-wide kv tiles (kv_end = q0+16)

    // ---- phase A: S once, cache e = exp2(s - m_wave) in registers ----
    f32x4 ec[4][2];
    float ml = MNEG;
#pragma unroll
    for (int j = 0; j < 4; ++j) {
        const int ti = w + 16 * j;
        if (ti < n32) {
            const int kvb = ti * 32;
            const u16* kr0 = kb + (size_t)(kvb + lr) * C_DIM;
            const u16* kr1 = kb + (size_t)(kvb + 16 + lr) * C_DIM;
            const bf16x8 k00 = *(const bf16x8*)(kr0 + lg * 8);
            const bf16x8 k01 = *(const bf16x8*)(kr0 + 32 + lg * 8);
            const bf16x8 k10 = *(const bf16x8*)(kr1 + lg * 8);
            const bf16x8 k11 = *(const bf16x8*)(kr1 + 32 + lg * 8);
            f32x4 s[2] = {};
            s[0] = __builtin_amdgcn_mfma_f32_16x16x32_bf16(k00, aq0, s[0], 0, 0, 0);
            s[0] = __builtin_amdgcn_mfma_f32_16x16x32_bf16(k01, aq1, s[0], 0, 0, 0);
            s[1] = __builtin_amdgcn_mfma_f32_16x16x32_bf16(k10, aq0, s[1], 0, 0, 0);
            s[1] = __builtin_amdgcn_mfma_f32_16x16x32_bf16(k11, aq1, s[1], 0, 0, 0);
#pragma unroll
            for (int t = 0; t < 2; ++t)
#pragma unroll
                for (int r = 0; r < 4; ++r) {
                    float v = s[t][r] * SC;
                    if (kvb + 16 * t + 4 * lg + r > qrow) v = MNEG;
                    ec[j][t][r] = v;
                    ml = fmaxf(ml, v);
                }
        } else {
#pragma unroll
            for (int t = 0; t < 2; ++t)
#pragma unroll
                for (int r = 0; r < 4; ++r) ec[j][t][r] = MNEG;
        }
    }
    ml = fmaxf(ml, __shfl_xor(ml, 16));
    ml = fmaxf(ml, __shfl_xor(ml, 32));
    float ll = 0.f;
#pragma unroll
    for (int j = 0; j < 4; ++j)
#pragma unroll
        for (int t = 0; t < 2; ++t)
#pragma unroll
            for (int r = 0; r < 4; ++r) {
                const float e = fexp2(ec[j][t][r] - ml);
                ec[j][t][r] = e;
                ll += e;
            }
    ll += __shfl_xor(ll, 16);
    ll += __shfl_xor(ll, 32);
    if (l < 16) { statm[w][lr] = ml; statl[w][lr] = ll; }
    __syncthreads();

    float mf = MNEG;
#pragma unroll
    for (int ww = 0; ww < 16; ++ww) mf = fmaxf(mf, statm[ww][lr]);
    float lf = 0.f;
#pragma unroll
    for (int ww = 0; ww < 16; ++ww) lf += statl[ww][lr] * fexp2(statm[ww][lr] - mf);
    const float scale = fexp2(ml - mf) / lf;

    // ---- phase B: P stores + PV from cached e (no K reload / QK MFMA) ----
    f32x4 cacc[4] = {};
#pragma unroll
    for (int j = 0; j < 4; ++j) {
        const int ti = w + 16 * j;
        if (ti < n32) {
            const int kvb = ti * 32;
            bf16x8 vf[4];
#pragma unroll
            for (int dt = 0; dt < 4; ++dt)
                vf[dt] = *(const bf16x8*)(vtb + (size_t)(dt * 16 + lr) * T_SEQ + kvb + lg * 8);
            u32 pw[2][2];
#pragma unroll
            for (int t2 = 0; t2 < 2; ++t2) {
                float p[4];
#pragma unroll
                for (int r = 0; r < 4; ++r) p[r] = ec[j][t2][r] * scale;
                f32x4 pv4 = { p[0], p[1], p[2], p[3] };
                __builtin_nontemporal_store(pv4,
                    (f32x4*)(ab + (size_t)qrow * T_SEQ + kvb + 16 * t2 + 4 * lg));
                pw[t2][0] = (u32)f2bf(p[0]) | ((u32)f2bf(p[1]) << 16);
                pw[t2][1] = (u32)f2bf(p[2]) | ((u32)f2bf(p[3]) << 16);
            }
            // shuffle-transpose: C-layout (kv in lg-groups of 4) -> A-frag (kv=8*lg+j)
            const int bl = lr + ((lg & 1) << 5);
            const u32 a0 = (u32)__shfl((int)pw[0][0], bl);
            const u32 a1 = (u32)__shfl((int)pw[0][1], bl);
            const u32 a2 = (u32)__shfl((int)pw[0][0], bl + 16);
            const u32 a3 = (u32)__shfl((int)pw[0][1], bl + 16);
            const u32 b0 = (u32)__shfl((int)pw[1][0], bl);
            const u32 b1 = (u32)__shfl((int)pw[1][1], bl);
            const u32 b2 = (u32)__shfl((int)pw[1][0], bl + 16);
            const u32 b3 = (u32)__shfl((int)pw[1][1], bl + 16);
            const bool hi2 = lg >= 2;
            union { u32 ww[4]; bf16x8 v; } pa;
            pa.ww[0] = hi2 ? b0 : a0;
            pa.ww[1] = hi2 ? b1 : a1;
            pa.ww[2] = hi2 ? b2 : a2;
            pa.ww[3] = hi2 ? b3 : a3;
            __builtin_amdgcn_s_setprio(1);
#pragma unroll
            for (int dt = 0; dt < 4; ++dt)
                cacc[dt] = __builtin_amdgcn_mfma_f32_16x16x32_bf16(pa.v, vf[dt], cacc[dt], 0, 0, 0);
            __builtin_amdgcn_s_setprio(0);
        }
    }

    // dump PV partials (cacc[dt][r] = ctx[q=4*lg+r][d=dt*16+lr])
    {
        float* pwv = pvbuf + w * PV_WS;
#pragma unroll
        for (int dt = 0; dt < 4; ++dt)
#pragma unroll
            for (int r = 0; r < 4; ++r)
                pwv[(4 * lg + r) * PV_QS + dt * 16 + lr] = cacc[dt][r];
    }
    __syncthreads();

    // reduce PV across 16 waves + write ctx (bf16): 1024 elems, 1 per thread
    {
        const int qq = tid >> 6;            // 0..15
        const int d0 = tid & 63;            // 0..63
        float s0 = 0.f;
#pragma unroll
        for (int ww = 0; ww < 16; ++ww)
            s0 += pvbuf[ww * PV_WS + qq * PV_QS + d0];
        u16* cb = ctx + bh_off;
        cb[(size_t)(q0 + qq) * C_DIM + d0] = f2bf(s0);
    }

    // zero-fill [n32*32, T) for all 16 rows (nontemporal streaming stores)
    {
        const int zs = n32 * 32;
        const int row = tid >> 6;
        const int c0 = (tid & 63) * 4;
        float* zr = ab + (size_t)(q0 + row) * T_SEQ;
        const f32x4 z4 = { 0.f, 0.f, 0.f, 0.f };
        for (int c = zs + c0; c < T_SEQ; c += 256)
            __builtin_nontemporal_store(z4, (f32x4*)(zr + c));
    }
}

// ---------------------------------------------------------------------------
extern "C" void kernel_launch(void* const* d_in, const int* in_sizes, int n_in,
                              void* d_out, int out_size, void* d_ws, size_t ws_size,
                              hipStream_t stream)
{
    const float* q  = (const float*)d_in[0];
    const float* k  = (const float*)d_in[1];
    const float* Wq = (const float*)d_in[2];
    const float* bq = (const float*)d_in[3];
    const float* Wk = (const float*)d_in[4];
    const float* bk = (const float*)d_in[5];
    const float* Wv = (const float*)d_in[6];
    const float* bv = (const float*)d_in[7];
    const float* Wo = (const float*)d_in[8];
    const float* bo = (const float*)d_in[9];
    (void)in_sizes; (void)n_in; (void)out_size; (void)ws_size;

    float* out = (float*)d_out;
    float* attn = out + (size_t)BATCH * T_SEQ * C_DIM;

    const size_t MC = (size_t)BATCH * T_SEQ * C_DIM;   // 4,194,304 elems
    u16* qp  = (u16*)d_ws;
    u16* kp  = qp + MC;
    u16* vt  = kp + MC;          // V^T: [B][H][D][T]
    u16* ctx = vt + MC;
    u16* WqT = ctx + MC;
    u16* WkT = WqT + (size_t)C_DIM * C_DIM;
    u16* WvT = WkT + (size_t)C_DIM * C_DIM;
    u16* WoT = WvT + (size_t)C_DIM * C_DIM;

    transpose_to_bf16<<<dim3(32, 32, 4), dim3(32, 8), 0, stream>>>(
        Wq, Wk, Wv, Wo, WqT, WkT, WvT, WoT);

    const int M = BATCH * T_SEQ;
    dim3 gqk(C_DIM / 128, M / 64, 2);
    dim3 g1(C_DIM / 128, M / 64, 1);
    // fused q & k projections (z selects pointer set)
    gemm_bt<true, 0><<<gqk, 256, 0, stream>>>(q, k, WqT, WkT, bq, bk,
                                              qp, kp, M, C_DIM, C_DIM);
    // vp = kp @ Wv -> V^T layout
    gemm_bt<false, 2><<<g1, 256, 0, stream>>>(kp, kp, WvT, WvT, bv, bv,
                                              vt, vt, M, C_DIM, C_DIM);

    attn_kernel<<<dim3(4096), 1024, 0, stream>>>(qp, kp, vt, ctx, attn);

    // out = ctx @ Wo (f32)
    gemm_bt<false, 1><<<g1, 256, 0, stream>>>(ctx, ctx, WoT, WoT, bo, bo,
                                              out, out, M, C_DIM, C_DIM);
}

// Round 9
// 254.161 us; speedup vs baseline: 1.7962x; 1.1327x over previous
//
#include <hip/hip_runtime.h>

typedef __attribute__((ext_vector_type(8))) short bf16x8;
typedef __attribute__((ext_vector_type(4))) float f32x4;
typedef unsigned short u16;
typedef unsigned int u32;

#define T_SEQ 2048
#define C_DIM 1024
#define NH 16
#define HD 64
#define BATCH 2

__device__ __forceinline__ u16 f2bf(float f) {
    union { float f; u32 u; } v; v.f = f;
    u32 u = v.u;
    u32 r = (u + 0x7FFFu + ((u >> 16) & 1u)) >> 16;
    return (u16)r;
}

__device__ __forceinline__ float fexp2(float x) { return __builtin_amdgcn_exp2f(x); }

__device__ __forceinline__ float bflo(u32 u) {   // low bf16 -> f32
    union { u32 u; float f; } v; v.u = u << 16; return v.f;
}
__device__ __forceinline__ float bfhi(u32 u) {   // high bf16 -> f32
    union { u32 u; float f; } v; v.u = u & 0xFFFF0000u; return v.f;
}

// async global->LDS, 16B per lane; LDS dest is wave-uniform base + lane*16
__device__ __forceinline__ void gld_lds16(const void* g, void* l) {
    __builtin_amdgcn_global_load_lds(
        (const __attribute__((address_space(1))) void*)g,
        (__attribute__((address_space(3))) void*)l, 16, 0, 0);
}

// ---------------------------------------------------------------------------
// Transpose 4 weight matrices [C,C] f32 -> [C,C] bf16 (WT[n][k] = W[k][n])
// ---------------------------------------------------------------------------
__global__ __launch_bounds__(256) void transpose_to_bf16(
    const float* __restrict__ W0, const float* __restrict__ W1,
    const float* __restrict__ W2, const float* __restrict__ W3,
    u16* __restrict__ O0, u16* __restrict__ O1,
    u16* __restrict__ O2, u16* __restrict__ O3)
{
    __shared__ float tile[32][33];
    const float* W = blockIdx.z == 0 ? W0 : blockIdx.z == 1 ? W1 : blockIdx.z == 2 ? W2 : W3;
    u16* O = blockIdx.z == 0 ? O0 : blockIdx.z == 1 ? O1 : blockIdx.z == 2 ? O2 : O3;
    const int tx = threadIdx.x, ty = threadIdx.y;
    const int bx = blockIdx.x * 32, by = blockIdx.y * 32;
#pragma unroll
    for (int i = 0; i < 4; ++i)
        tile[ty + i * 8][tx] = W[(size_t)(by + ty + i * 8) * C_DIM + bx + tx];
    __syncthreads();
#pragma unroll
    for (int i = 0; i < 4; ++i)
        O[(size_t)(bx + ty + i * 8) * C_DIM + by + tx] = f2bf(tile[tx][ty + i * 8]);
}

// ---------------------------------------------------------------------------
// GEMM: Y[M,N] = X[M,K] @ W[K,N] + bias, WT[N,K] pre-transposed bf16.
// 64x128 (MxN) tile, BK=32, 4 waves (each 64 rows x 32 cols, acc 4x2).
// Grid (N/128, M/64, nz); blockIdx.z selects pointer set (q/k fusion).
// OMODE: 0 = bf16 row-major, 1 = f32 row-major, 2 = bf16 per-head V^T
// ---------------------------------------------------------------------------
template<bool XF32, int OMODE>
__global__ __launch_bounds__(256) void gemm_bt(
    const void* __restrict__ X0_, const void* __restrict__ X1_,
    const u16* __restrict__ W0T, const u16* __restrict__ W1T,
    const float* __restrict__ b0_, const float* __restrict__ b1_,
    void* __restrict__ Y0_, void* __restrict__ Y1_,
    int M, int N, int K)
{
    __shared__ u16 As[64 * 32];
    __shared__ u16 Bs[128 * 32];
    const int tid = threadIdx.x;
    const int w = tid >> 6, l = tid & 63;
    const int lr = l & 15, lg = l >> 4;
    const int z = blockIdx.z;
    const void* Xv = z ? X1_ : X0_;
    const u16* WT = z ? W1T : W0T;
    const float* bias = z ? b1_ : b0_;
    void* Yv = z ? Y1_ : Y0_;
    const int m0 = blockIdx.y * 64, n0 = blockIdx.x * 128;
    const int grow = l >> 2, gcol = (l & 3) * 8;
    f32x4 acc[4][2] = {};

    for (int k0 = 0; k0 < K; k0 += 32) {
        __syncthreads();
        if (XF32) {
            // 256 threads stage A: 64 rows x 32 cols (f32 -> bf16)
            const int row = tid >> 2, cg = tid & 3;
            const float* g = (const float*)Xv + (size_t)(m0 + row) * K + k0 + cg * 8;
            float4 a0 = *(const float4*)g;
            float4 a1 = *(const float4*)(g + 4);
            union { u16 h[8]; uint4 q; } pk;
            pk.h[0] = f2bf(a0.x); pk.h[1] = f2bf(a0.y);
            pk.h[2] = f2bf(a0.z); pk.h[3] = f2bf(a0.w);
            pk.h[4] = f2bf(a1.x); pk.h[5] = f2bf(a1.y);
            pk.h[6] = f2bf(a1.z); pk.h[7] = f2bf(a1.w);
            *(uint4*)&As[row * 32 + cg * 8] = pk.q;
        } else {
            // wave w stages A rows [w*16, w*16+16)
            gld_lds16((const u16*)Xv + (size_t)(m0 + w * 16 + grow) * K + k0 + gcol,
                      &As[w * 512]);
        }
        // wave w stages B rows [w*32, w*32+32) in 2 insts
#pragma unroll
        for (int i = 0; i < 2; ++i)
            gld_lds16(WT + (size_t)(n0 + w * 32 + i * 16 + grow) * K + k0 + gcol,
                      &Bs[(w * 2 + i) * 512]);
        __syncthreads();
        bf16x8 af[4], bfr[2];
#pragma unroll
        for (int i = 0; i < 4; ++i)
            af[i] = *(const bf16x8*)&As[(i * 16 + lr) * 32 + lg * 8];
#pragma unroll
        for (int j = 0; j < 2; ++j)
            bfr[j] = *(const bf16x8*)&Bs[(w * 32 + j * 16 + lr) * 32 + lg * 8];
#pragma unroll
        for (int i = 0; i < 4; ++i)
#pragma unroll
            for (int j = 0; j < 2; ++j)
                acc[i][j] = __builtin_amdgcn_mfma_f32_16x16x32_bf16(af[i], bfr[j], acc[i][j], 0, 0, 0);
    }

#pragma unroll
    for (int i = 0; i < 4; ++i) {
        const int rowb = m0 + i * 16 + lg * 4;
#pragma unroll
        for (int j = 0; j < 2; ++j) {
            const int col = n0 + w * 32 + j * 16 + lr;
            const float bv = bias[col];
            if (OMODE == 2) {
                union { u16 h[4]; uint2 q; } pk;
#pragma unroll
                for (int r = 0; r < 4; ++r) pk.h[r] = f2bf(acc[i][j][r] + bv);
                const int bb = rowb >> 11, tt = rowb & 2047;
                const int hh = col >> 6, dd = col & 63;
                u16* dst = (u16*)Yv + ((size_t)((bb * NH + hh) * HD + dd)) * T_SEQ + tt;
                *(uint2*)dst = pk.q;
            } else {
#pragma unroll
                for (int r = 0; r < 4; ++r) {
                    const float v = acc[i][j][r] + bv;
                    if (OMODE == 1)
                        ((float*)Yv)[(size_t)(rowb + r) * N + col] = v;
                    else
                        ((u16*)Yv)[(size_t)(rowb + r) * N + col] = f2bf(v);
                }
            }
        }
    }
}

// ---------------------------------------------------------------------------
// Causal attention. Block = (b, h, 16 q-rows), 8 waves (512 thr) -> 2 blocks
// resident per CU (independent barrier domains overlap).
// kv split in 32-wide tiles, up to 8 per wave (ti = w + 8*j).
// Phase 0: zero-fill upper region (independent; overlaps phase A).
// Phase A: S once; per tile cache mt_j (lane max), S_j (lane sumexp), and
//          e = exp2(s - mt_j) packed as 2xbf16 per u32 (16 VGPR for 8 tiles).
// Phase B: p = e * exp2(mt_j - mf)/lf; nontemporal P stores; shfl-transpose
//          into PV A-frag; setprio around PV MFMA.
// Grid flattened + XCD-swizzled so each XCD owns 4 consecutive heads.
// ---------------------------------------------------------------------------
#define PV_QS 67                 // float stride per q-row in pvbuf
#define PV_WS (16 * PV_QS + 8)   // float stride per wave block

__global__ __launch_bounds__(512, 4) void attn_kernel(
    const u16* __restrict__ qp, const u16* __restrict__ kp,
    const u16* __restrict__ vt, u16* __restrict__ ctx,
    float* __restrict__ attn)
{
    __shared__ float statm[8][16], statl[8][16];
    __shared__ float pvbuf[8 * PV_WS];

    const int tid = threadIdx.x;
    const int w = tid >> 6, l = tid & 63;
    const int lr = l & 15, lg = l >> 4;

    // XCD-aware bijective swizzle: 4096 blocks, 8 XCDs, 512 blocks each.
    const int wgid = (blockIdx.x & 7) * 512 + (blockIdx.x >> 3);
    const int b = wgid >> 11;
    const int h = (wgid >> 7) & 15;
    const int strip = 127 - (wgid & 127);   // heavy-first within XCD chunk
    const int q0 = strip * 16;

    const size_t bh_off = (size_t)b * T_SEQ * C_DIM + h * HD;
    const u16* qb = qp + bh_off;
    const u16* kb = kp + bh_off;
    const u16* vtb = vt + ((size_t)(b * NH + h) * HD) * T_SEQ;
    float* ab = attn + (size_t)(b * NH + h) * T_SEQ * T_SEQ;

    const float SC = 0.125f * 1.44269504088896f;   // 1/sqrt(64) * log2(e)
    const float MNEG = -1e30f;

    const int qrow = q0 + lr;
    const int n32 = (q0 + 47) >> 5;       // 32-wide kv tiles (kv_end = q0+16)

    // ---- phase 0: zero-fill upper region (independent, overlaps A) ----
    {
        const int zs = n32 * 32;
        const int row = tid >> 5;           // 0..15
        const int c0 = (tid & 31) * 4;
        float* zr = ab + (size_t)(q0 + row) * T_SEQ;
        const f32x4 z4 = { 0.f, 0.f, 0.f, 0.f };
        for (int c = zs + c0; c < T_SEQ; c += 128)
            __builtin_nontemporal_store(z4, (f32x4*)(zr + c));
    }

    const bf16x8 aq0 = *(const bf16x8*)(qb + (size_t)(q0 + lr) * C_DIM + lg * 8);
    const bf16x8 aq1 = *(const bf16x8*)(qb + (size_t)(q0 + lr) * C_DIM + 32 + lg * 8);

    // ---- phase A: S once; cache mt_j, S_j, packed e per tile ----
    u32 ec[8][2];     // e packed 2xbf16: [j][t2] = (e[r=0],e[r=1]) | (e2,e3)... see below
    u32 ec2[8][2];    // second pair per t2: layout [j][t2] words 0..1 = r0r1, r2r3
    float mtj[8], Sj[8];
    float ml = MNEG;
#pragma unroll
    for (int j = 0; j < 8; ++j) {
        const int ti = w + 8 * j;
        if (ti < n32) {
            const int kvb = ti * 32;
            const u16* kr0 = kb + (size_t)(kvb + lr) * C_DIM;
            const u16* kr1 = kb + (size_t)(kvb + 16 + lr) * C_DIM;
            const bf16x8 k00 = *(const bf16x8*)(kr0 + lg * 8);
            const bf16x8 k01 = *(const bf16x8*)(kr0 + 32 + lg * 8);
            const bf16x8 k10 = *(const bf16x8*)(kr1 + lg * 8);
            const bf16x8 k11 = *(const bf16x8*)(kr1 + 32 + lg * 8);
            f32x4 s[2] = {};
            s[0] = __builtin_amdgcn_mfma_f32_16x16x32_bf16(k00, aq0, s[0], 0, 0, 0);
            s[0] = __builtin_amdgcn_mfma_f32_16x16x32_bf16(k01, aq1, s[0], 0, 0, 0);
            s[1] = __builtin_amdgcn_mfma_f32_16x16x32_bf16(k10, aq0, s[1], 0, 0, 0);
            s[1] = __builtin_amdgcn_mfma_f32_16x16x32_bf16(k11, aq1, s[1], 0, 0, 0);
            float sv[2][4];
            float mt = MNEG;
#pragma unroll
            for (int t = 0; t < 2; ++t)
#pragma unroll
                for (int r = 0; r < 4; ++r) {
                    float v = s[t][r] * SC;
                    if (kvb + 16 * t + 4 * lg + r > qrow) v = MNEG;
                    sv[t][r] = v;
                    mt = fmaxf(mt, v);
                }
            mtj[j] = mt;
            float ss = 0.f;
            float e[2][4];
#pragma unroll
            for (int t = 0; t < 2; ++t)
#pragma unroll
                for (int r = 0; r < 4; ++r) {
                    e[t][r] = fexp2(sv[t][r] - mt);
                    ss += e[t][r];
                }
            Sj[j] = ss;
#pragma unroll
            for (int t = 0; t < 2; ++t) {
                ec[j][t]  = (u32)f2bf(e[t][0]) | ((u32)f2bf(e[t][1]) << 16);
                ec2[j][t] = (u32)f2bf(e[t][2]) | ((u32)f2bf(e[t][3]) << 16);
            }
            ml = fmaxf(ml, mt);
        } else {
            mtj[j] = MNEG; Sj[j] = 0.f;
            ec[j][0] = ec[j][1] = ec2[j][0] = ec2[j][1] = 0;
        }
    }
    float ll = 0.f;
#pragma unroll
    for (int j = 0; j < 8; ++j) ll += Sj[j] * fexp2(mtj[j] - ml);
    // cross-lane (lg) combine
#pragma unroll
    for (int d = 16; d <= 32; d <<= 1) {
        const float mo = __shfl_xor(ml, d);
        const float lo = __shfl_xor(ll, d);
        const float mn = fmaxf(ml, mo);
        ll = ll * fexp2(ml - mn) + lo * fexp2(mo - mn);
        ml = mn;
    }
    if (l < 16) { statm[w][lr] = ml; statl[w][lr] = ll; }
    __syncthreads();

    float mf = MNEG;
#pragma unroll
    for (int ww = 0; ww < 8; ++ww) mf = fmaxf(mf, statm[ww][lr]);
    float lf = 0.f;
#pragma unroll
    for (int ww = 0; ww < 8; ++ww) lf += statl[ww][lr] * fexp2(statm[ww][lr] - mf);
    const float rlf = 1.f / lf;

    // ---- phase B: P stores + PV from cached e ----
    f32x4 cacc[4] = {};
#pragma unroll
    for (int j = 0; j < 8; ++j) {
        const int ti = w + 8 * j;
        if (ti < n32) {
            const int kvb = ti * 32;
            bf16x8 vf[4];
#pragma unroll
            for (int dt = 0; dt < 4; ++dt)
                vf[dt] = *(const bf16x8*)(vtb + (size_t)(dt * 16 + lr) * T_SEQ + kvb + lg * 8);
            const float scale = fexp2(mtj[j] - mf) * rlf;
            u32 pw[2][2];
#pragma unroll
            for (int t2 = 0; t2 < 2; ++t2) {
                float p[4];
                p[0] = bflo(ec[j][t2]) * scale;
                p[1] = bfhi(ec[j][t2]) * scale;
                p[2] = bflo(ec2[j][t2]) * scale;
                p[3] = bfhi(ec2[j][t2]) * scale;
                f32x4 pv4 = { p[0], p[1], p[2], p[3] };
                __builtin_nontemporal_store(pv4,
                    (f32x4*)(ab + (size_t)qrow * T_SEQ + kvb + 16 * t2 + 4 * lg));
                pw[t2][0] = (u32)f2bf(p[0]) | ((u32)f2bf(p[1]) << 16);
                pw[t2][1] = (u32)f2bf(p[2]) | ((u32)f2bf(p[3]) << 16);
            }
            // shuffle-transpose: C-layout (kv in lg-groups of 4) -> A-frag (kv=8*lg+jj)
            const int bl = lr + ((lg & 1) << 5);
            const u32 a0 = (u32)__shfl((int)pw[0][0], bl);
            const u32 a1 = (u32)__shfl((int)pw[0][1], bl);
            const u32 a2 = (u32)__shfl((int)pw[0][0], bl + 16);
            const u32 a3 = (u32)__shfl((int)pw[0][1], bl + 16);
            const u32 b0 = (u32)__shfl((int)pw[1][0], bl);
            const u32 b1 = (u32)__shfl((int)pw[1][1], bl);
            const u32 b2 = (u32)__shfl((int)pw[1][0], bl + 16);
            const u32 b3 = (u32)__shfl((int)pw[1][1], bl + 16);
            const bool hi2 = lg >= 2;
            union { u32 ww[4]; bf16x8 v; } pa;
            pa.ww[0] = hi2 ? b0 : a0;
            pa.ww[1] = hi2 ? b1 : a1;
            pa.ww[2] = hi2 ? b2 : a2;
            pa.ww[3] = hi2 ? b3 : a3;
            __builtin_amdgcn_s_setprio(1);
#pragma unroll
            for (int dt = 0; dt < 4; ++dt)
                cacc[dt] = __builtin_amdgcn_mfma_f32_16x16x32_bf16(pa.v, vf[dt], cacc[dt], 0, 0, 0);
            __builtin_amdgcn_s_setprio(0);
        }
    }

    // dump PV partials (cacc[dt][r] = ctx[q=4*lg+r][d=dt*16+lr])
    {
        float* pwv = pvbuf + w * PV_WS;
#pragma unroll
        for (int dt = 0; dt < 4; ++dt)
#pragma unroll
            for (int r = 0; r < 4; ++r)
                pwv[(4 * lg + r) * PV_QS + dt * 16 + lr] = cacc[dt][r];
    }
    __syncthreads();

    // reduce PV across 8 waves + write ctx (bf16): 1024 elems, 512 thr x 2
    {
        const int qq = tid >> 5;            // 0..15
        const int d0 = (tid & 31) * 2;      // 0..62
        float s0 = 0.f, s1 = 0.f;
#pragma unroll
        for (int ww = 0; ww < 8; ++ww) {
            const float* pwv = pvbuf + ww * PV_WS + qq * PV_QS;
            s0 += pwv[d0];
            s1 += pwv[d0 + 1];
        }
        union { u16 hh[2]; u32 u; } pk;
        pk.hh[0] = f2bf(s0); pk.hh[1] = f2bf(s1);
        u16* cb = ctx + bh_off;
        *(u32*)(cb + (size_t)(q0 + qq) * C_DIM + d0) = pk.u;
    }
}

// ---------------------------------------------------------------------------
extern "C" void kernel_launch(void* const* d_in, const int* in_sizes, int n_in,
                              void* d_out, int out_size, void* d_ws, size_t ws_size,
                              hipStream_t stream)
{
    const float* q  = (const float*)d_in[0];
    const float* k  = (const float*)d_in[1];
    const float* Wq = (const float*)d_in[2];
    const float* bq = (const float*)d_in[3];
    const float* Wk = (const float*)d_in[4];
    const float* bk = (const float*)d_in[5];
    const float* Wv = (const float*)d_in[6];
    const float* bv = (const float*)d_in[7];
    const float* Wo = (const float*)d_in[8];
    const float* bo = (const float*)d_in[9];
    (void)in_sizes; (void)n_in; (void)out_size; (void)ws_size;

    float* out = (float*)d_out;
    float* attn = out + (size_t)BATCH * T_SEQ * C_DIM;

    const size_t MC = (size_t)BATCH * T_SEQ * C_DIM;   // 4,194,304 elems
    u16* qp  = (u16*)d_ws;
    u16* kp  = qp + MC;
    u16* vt  = kp + MC;          // V^T: [B][H][D][T]
    u16* ctx = vt + MC;
    u16* WqT = ctx + MC;
    u16* WkT = WqT + (size_t)C_DIM * C_DIM;
    u16* WvT = WkT + (size_t)C_DIM * C_DIM;
    u16* WoT = WvT + (size_t)C_DIM * C_DIM;

    transpose_to_bf16<<<dim3(32, 32, 4), dim3(32, 8), 0, stream>>>(
        Wq, Wk, Wv, Wo, WqT, WkT, WvT, WoT);

    const int M = BATCH * T_SEQ;
    dim3 gqk(C_DIM / 128, M / 64, 2);
    dim3 g1(C_DIM / 128, M / 64, 1);
    // fused q & k projections (z selects pointer set)
    gemm_bt<true, 0><<<gqk, 256, 0, stream>>>(q, k, WqT, WkT, bq, bk,
                                              qp, kp, M, C_DIM, C_DIM);
    // vp = kp @ Wv -> V^T layout
    gemm_bt<false, 2><<<g1, 256, 0, stream>>>(kp, kp, WvT, WvT, bv, bv,
                                              vt, vt, M, C_DIM, C_DIM);

    attn_kernel<<<dim3(4096), 512, 0, stream>>>(qp, kp, vt, ctx, attn);

    // out = ctx @ Wo (f32)
    gemm_bt<false, 1><<<g1, 256, 0, stream>>>(ctx, ctx, WoT, WoT, bo, bo,
                                              out, out, M, C_DIM, C_DIM);
}